// Round 1
// baseline (1303.403 us; speedup 1.0000x reference)
//
#include <hip/hip_runtime.h>
#include <hip/hip_bf16.h>
#include <stdint.h>

#define AS1 __attribute__((address_space(1)))
#define AS3 __attribute__((address_space(3)))

typedef short s16x8 __attribute__((ext_vector_type(8)));
typedef float f32x16 __attribute__((ext_vector_type(16)));
typedef __bf16 bf16x8_t __attribute__((ext_vector_type(8)));

union ABFrag { bf16x8_t h; s16x8 s; };

__device__ __forceinline__ ushort f2b_rne(float f){
  uint32_t u = __float_as_uint(f);
  u += 0x7fffu + ((u >> 16) & 1u);
  return (ushort)(u >> 16);
}

// ---------------------------------------------------------------------------
// Pack W: fp32 [A=128][N=64][M=64][O=64] -> bf16 fragment-ordered stream.
// ws bf16 element index:
//   (n*64+m)*8192 + (s*4+wn)*512 + (g*32+la)*8 + i
//     = bf16( W[a=wn*32+la][n][m][o=s*16+g*8+i] )
// One thread per (n,m,a); a fastest -> coalesced 16B writes per 32-lane group.
// ---------------------------------------------------------------------------
__global__ __launch_bounds__(256) void pack_w_kernel(const float* __restrict__ W,
                                                     ushort* __restrict__ wsp){
  const int u  = blockIdx.x * 256 + threadIdx.x;   // (n*64+m)*128 + a
  const int a  = u & 127;
  const int nm = u >> 7;            // n*64 + m
  const int n  = nm >> 6;
  const int m  = nm & 63;
  const float* src = W + ((size_t)a << 18) + ((size_t)n << 12) + ((size_t)m << 6);
  ushort* dst = wsp + (size_t)nm * 8192;
  const int wn = a >> 5, la = a & 31;
  #pragma unroll
  for (int s = 0; s < 4; ++s){
    #pragma unroll
    for (int g = 0; g < 2; ++g){
      const float4 f0 = *(const float4*)(src + s*16 + g*8);
      const float4 f1 = *(const float4*)(src + s*16 + g*8 + 4);
      uint4 o;
      o.x = (uint32_t)f2b_rne(f0.x) | ((uint32_t)f2b_rne(f0.y) << 16);
      o.y = (uint32_t)f2b_rne(f0.z) | ((uint32_t)f2b_rne(f0.w) << 16);
      o.z = (uint32_t)f2b_rne(f1.x) | ((uint32_t)f2b_rne(f1.y) << 16);
      o.w = (uint32_t)f2b_rne(f1.z) | ((uint32_t)f2b_rne(f1.w) << 16);
      *(uint4*)(dst + (s*4 + wn)*512 + (g*32 + la)*8) = o;
    }
  }
}

// ---------------------------------------------------------------------------
// GEMM: out[b,a] += sum_n x1[b,n] * ( sum_{m,o} (x2[b,m]*x3[b,o]) * W[a,n,m,o] )
// 256 rows/block, 8 waves x 32 rows, BN=128 (full A), split-K=4 over n.
// A-operand generated in registers (rank-1: x2[m]-scalar * x3 row regs).
// B staged via global_load_lds, double-buffered, m97-style 1 barrier/iter.
// mfma_f32_32x32x16_bf16; D layout: col=lane&31, row=(r&3)+8*(r>>2)+4*(lane>>5).
// ---------------------------------------------------------------------------
__global__ __launch_bounds__(512, 2) void trilinear_gemm_kernel(
    const float* __restrict__ x1g, const float* __restrict__ x2g,
    const float* __restrict__ x3g, const ushort* __restrict__ wsp,
    const float* __restrict__ biasg, float* __restrict__ outg){

  __shared__ __align__(16) char Bbuf[2 * 16384];
  __shared__ ushort x2s[256 * 64];
  __shared__ ushort x1s[256 * 64];

  const int tid  = threadIdx.x;
  const int wave = tid >> 6;
  const int lane = tid & 63;
  const int la   = lane & 31;
  const int lg   = lane >> 5;

  const int bid      = blockIdx.x;
  const int g8       = bid & 7;                       // XCD id (round-robin dispatch)
  const int nsplit   = g8 & 3;                        // same n-range within an XCD -> L2 reuse
  const int row_tile = (bid >> 3) | ((g8 >> 2) << 5);
  const int row0     = row_tile * 256;
  const int n0       = nsplit * 16;

  // ---- stage x1/x2 tiles to LDS as bf16, staggered columns (conflict-free reads)
  #pragma unroll
  for (int j = 0; j < 32; ++j){
    const int e = tid + 512 * j;
    const int r = e >> 6, c = e & 63;
    const int cc = (c + r) & 63;
    x2s[r*64 + cc] = f2b_rne(x2g[(size_t)row0*64 + e]);
    x1s[r*64 + cc] = f2b_rne(x1g[(size_t)row0*64 + e]);
  }

  // ---- this lane's x3 row -> 32 fp32 registers (only its k-group's o values)
  const int arow = row0 + wave*32 + la;
  float x3r[32];
  #pragma unroll
  for (int s = 0; s < 4; ++s){
    const float4 p0 = *(const float4*)(x3g + (size_t)arow*64 + s*16 + lg*8);
    const float4 p1 = *(const float4*)(x3g + (size_t)arow*64 + s*16 + lg*8 + 4);
    x3r[s*8+0]=p0.x; x3r[s*8+1]=p0.y; x3r[s*8+2]=p0.z; x3r[s*8+3]=p0.w;
    x3r[s*8+4]=p1.x; x3r[s*8+5]=p1.y; x3r[s*8+6]=p1.z; x3r[s*8+7]=p1.w;
  }

  f32x16 tacc[4], macc[4];
  #pragma unroll
  for (int wn = 0; wn < 4; ++wn){ tacc[wn] = 0.f; macc[wn] = 0.f; }

  const ushort* wbase = wsp + (size_t)n0 * 64 * 8192;

  // prologue: stage K-block 0 into buffer 0 (linear: dst = wave base + lane*16)
  {
    const char* sp = (const char*)wbase + wave*2048 + lane*16;
    char* dp = Bbuf + wave*2048;
    __builtin_amdgcn_global_load_lds((const AS1 uint32_t*)sp,        (AS3 uint32_t*)dp,        16, 0, 0);
    __builtin_amdgcn_global_load_lds((const AS1 uint32_t*)(sp+1024), (AS3 uint32_t*)(dp+1024), 16, 0, 0);
  }
  __syncthreads();   // covers x1s/x2s stores + block-0 DMA (vmcnt(0) at barrier)

  const int rl = wave*32 + la;
  int cur = 0;

  for (int blk = 0; blk < 1024; ++blk){          // 16 n per block x 64 m
    // stage next K-block into the other buffer (lands by next barrier)
    if (blk + 1 < 1024){
      const char* sp = (const char*)wbase + (size_t)(blk + 1) * 16384 + wave*2048 + lane*16;
      char* dp = Bbuf + (cur ^ 1) * 16384 + wave*2048;
      __builtin_amdgcn_global_load_lds((const AS1 uint32_t*)sp,        (AS3 uint32_t*)dp,        16, 0, 0);
      __builtin_amdgcn_global_load_lds((const AS1 uint32_t*)(sp+1024), (AS3 uint32_t*)(dp+1024), 16, 0, 0);
    }

    // A-fragments: U[row][o] = x2[row][m] * x3[row][o], bf16
    const int m = blk & 63;
    const uint32_t cb = x2s[rl*64 + ((m + rl) & 63)];
    const float c = __uint_as_float(cb << 16);

    ABFrag af[4];
    #pragma unroll
    for (int s = 0; s < 4; ++s){
      #pragma unroll
      for (int i = 0; i < 8; ++i)
        af[s].h[i] = (__bf16)(c * x3r[s*8 + i]);
    }

    // 16 MFMAs: 4 K-steps x 4 col-fragments
    const char* bb = Bbuf + cur * 16384 + (lane << 4);
    #pragma unroll
    for (int s = 0; s < 4; ++s){
      #pragma unroll
      for (int wn = 0; wn < 4; ++wn){
        const s16x8 bf = *(const s16x8*)(bb + ((s*4 + wn) << 10));
        tacc[wn] = __builtin_amdgcn_mfma_f32_32x32x16_bf16(af[s].s, bf, tacc[wn], 0, 0, 0);
      }
    }

    // n boundary: fold tacc into macc scaled by x1[row][n], reset tacc
    if (m == 63){
      const int n = n0 + (blk >> 6);
      #pragma unroll
      for (int r = 0; r < 16; ++r){
        const int rloc = wave*32 + (r & 3) + 8*(r >> 2) + 4*lg;
        const uint32_t xb = x1s[rloc*64 + ((n + rloc) & 63)];   // broadcast read
        const float xv = __uint_as_float(xb << 16);
        #pragma unroll
        for (int wn = 0; wn < 4; ++wn){
          macc[wn][r] += xv * tacc[wn][r];
          tacc[wn][r] = 0.f;
        }
      }
    }
    __syncthreads();
    cur ^= 1;
  }

  // ---- epilogue: atomic accumulate split-K partials; split 0 carries bias
  #pragma unroll
  for (int wn = 0; wn < 4; ++wn){
    const int col = wn*32 + la;
    const float bv = (nsplit == 0) ? biasg[col] : 0.f;
    #pragma unroll
    for (int r = 0; r < 16; ++r){
      const int row = row0 + wave*32 + (r & 3) + 8*(r >> 2) + 4*lg;
      atomicAdd(outg + (size_t)row*128 + col, macc[wn][r] + bv);
    }
  }
}

// ---------------------------------------------------------------------------
extern "C" void kernel_launch(void* const* d_in, const int* in_sizes, int n_in,
                              void* d_out, int out_size, void* d_ws, size_t ws_size,
                              hipStream_t stream){
  const float* x1   = (const float*)d_in[0];
  const float* x2   = (const float*)d_in[1];
  const float* x3   = (const float*)d_in[2];
  const float* W    = (const float*)d_in[3];
  const float* bias = (const float*)d_in[4];
  float* out = (float*)d_out;

  // d_out is re-poisoned before every launch: zero it (split-K accumulates on top)
  hipMemsetAsync(d_out, 0, (size_t)16384 * 128 * sizeof(float), stream);

  // need 64 MB of scratch for the bf16-packed W
  if (ws_size < (size_t)64 * 1024 * 1024) return;  // leaves zeros -> diagnostic absmax ~246

  ushort* wsp = (ushort*)d_ws;
  pack_w_kernel<<<2048, 256, 0, stream>>>(W, wsp);
  trilinear_gemm_kernel<<<256, 512, 0, stream>>>(x1, x2, x3, wsp, bias, out);
}